// Round 5
// baseline (298.276 us; speedup 1.0000x reference)
//
#include <hip/hip_runtime.h>

#define N_NODES 50000
#define FEAT    128
#define NEDGE   600000
#define BLK_PER_HALF 782   // ceil(50000/64)

#define NBUK    196        // buckets per rel (256 dsts each); 588 total
#define NBUKT   588
#define BUKCAP  4096       // bucket total: mean 3061, sigma 55 -> 19 sigma
#define KPART   224        // partition blocks
#define SEGCAP  56         // mean 13.7, Poisson tail @56 ~ 1e-16/segment
#define SEGQ    14         // SEGCAP/4 uint4s
#define EPB     2679       // ceil(600000/224)
#define NB_CVT  6250       // 2 x 3125
#define NB_W    5

typedef __attribute__((ext_vector_type(8))) short short8;
typedef __attribute__((ext_vector_type(4))) float f32x4;

// ---------- bf16 helpers ----------
__device__ __forceinline__ unsigned short f2bf(float f) {
  unsigned u = __float_as_uint(f);
  return (unsigned short)((u + 0x7fffu + ((u >> 16) & 1u)) >> 16);
}
__device__ __forceinline__ float bflo(unsigned u) { return __uint_as_float(u << 16); }
__device__ __forceinline__ float bfhi(unsigned u) { return __uint_as_float(u & 0xffff0000u); }

__device__ __forceinline__ int edge_at(const void* __restrict__ edges, long i, int is64) {
  return is64 ? (int)((const long long*)edges)[i] : ((const int*)edges)[i];
}

// ---------- fused: LDS-staged partition + x->bf16 conversion + W pack ----------
// Partition: per-rel passes; segments staged in LDS (no scattered global
// stores in the hot loop), flushed as contiguous 224-B uint4 runs.
// part layout TRANSPOSED: part[(bucket*KPART + block)*SEGCAP + pos]
// -> a bucket's 224 segments are one contiguous ~50 KB region for csr_build.
__global__ __launch_bounds__(256) void part_cvt(
    const void* __restrict__ e0, const void* __restrict__ e1, const void* __restrict__ e2,
    unsigned* __restrict__ part, int* __restrict__ countsT, int* __restrict__ btot,
    const float* __restrict__ xu, const float* __restrict__ xi,
    const float* __restrict__ W_fol, const float* __restrict__ W_bb,
    const float* __restrict__ W_lu, const float* __restrict__ W_buy,
    const float* __restrict__ W_li,
    unsigned short* __restrict__ xu_b, unsigned short* __restrict__ xi_b,
    unsigned short* __restrict__ wfrag) {
  __shared__ unsigned stg[NBUK * SEGCAP];   // 43904 B staging
  __shared__ int scnt[NBUK];
  __shared__ int s_is64;
  int b = blockIdx.x;
  int t = threadIdx.x;
  if (b < KPART) {
    // inline dtype detect: wave 0 samples the first 64 u32-pair hi words
    if (t < 64) {
      unsigned hi = ((const unsigned*)e0)[2 * t + 1];
      unsigned long long any = __ballot(hi != 0u);
      if (t == 0) s_is64 = (any == 0ull) ? 1 : 0;
    }
    __syncthreads();
    int is64 = s_is64;
    const void* es[3] = {e0, e1, e2};
    int ebase = b * EPB;
    int eend = min(ebase + EPB, NEDGE);
    for (int rel = 0; rel < 3; ++rel) {
      for (int i = t; i < NBUK; i += 256) scnt[i] = 0;
      __syncthreads();
      const void* ep = es[rel];
      for (int ei = ebase + t; ei < eend; ei += 256) {
        int src = edge_at(ep, ei, is64);
        int dst = edge_at(ep, (long)NEDGE + ei, is64);
        int bk = dst >> 8;
        int pos = atomicAdd(&scnt[bk], 1);
        if (pos < SEGCAP)
          stg[bk * SEGCAP + pos] = (unsigned)src | ((unsigned)(dst & 255) << 16);
      }
      __syncthreads();
      // coalesced flush: full segments (stale tail entries bounded by countsT)
      const uint4* s4 = (const uint4*)stg;
      uint4* p4 = (uint4*)part;
      for (int i = t; i < NBUK * SEGQ; i += 256) {
        int bk = i / SEGQ, j = i - bk * SEGQ;
        p4[((size_t)((rel * NBUK + bk) * KPART + b)) * SEGQ + j] = s4[i];
      }
      for (int i = t; i < NBUK; i += 256) {
        int c = min(scnt[i], SEGCAP);
        countsT[(rel * NBUK + i) * KPART + b] = c;
        atomicAdd(&btot[rel * NBUK + i], c);   // cross-block totals (pre-zeroed)
      }
      __syncthreads();   // before reusing scnt/stg for next rel
    }
  } else if (b < KPART + NB_CVT) {
    int cb = b - KPART;
    const float* src = (cb < 3125) ? xu : xi;
    unsigned short* dst = (cb < 3125) ? xu_b : xi_b;
    int lb = (cb < 3125) ? cb : cb - 3125;
    size_t base = ((size_t)lb * 256 + t) * 8;
    float4 v0 = *reinterpret_cast<const float4*>(src + base);
    float4 v1 = *reinterpret_cast<const float4*>(src + base + 4);
    uint4 o;
    o.x = f2bf(v0.x) | ((unsigned)f2bf(v0.y) << 16);
    o.y = f2bf(v0.z) | ((unsigned)f2bf(v0.w) << 16);
    o.z = f2bf(v1.x) | ((unsigned)f2bf(v1.y) << 16);
    o.w = f2bf(v1.z) | ((unsigned)f2bf(v1.w) << 16);
    *reinterpret_cast<uint4*>(dst + base) = o;
  } else {
    int s = b - (KPART + NB_CVT);
    const float* W = (s == 0) ? W_fol : (s == 1) ? W_bb : (s == 2) ? W_lu
                    : (s == 3) ? W_buy : W_li;
    for (int idx = t; idx < 16384; idx += 256) {
      int k = idx >> 7, n = idx & 127;
      int kc = k >> 5, q = (k >> 3) & 3, j = k & 7;
      int nt = n >> 4, nl = n & 15;
      wfrag[((((size_t)s * 4 + kc) * 8 + nt) * 64 + (q * 16 + nl)) * 8 + j] = f2bf(W[idx]);
    }
  }
}

// ---------- block scan helper ----------
__device__ __forceinline__ int block_scan_incl(int v, int* wsum) {
  int lane = threadIdx.x & 63, wid = threadIdx.x >> 6;
#pragma unroll
  for (int d = 1; d < 64; d <<= 1) {
    int n = __shfl_up(v, d, 64);
    if (lane >= d) v += n;
  }
  if (lane == 63) wsum[wid] = v;
  __syncthreads();
  if (threadIdx.x < 4) {
    int s = wsum[threadIdx.x];
#pragma unroll
    for (int d = 1; d < 4; d <<= 1) {
      int n = __shfl_up(s, d, 64);
      if ((int)threadIdx.x >= d) s += n;
    }
    wsum[threadIdx.x] = s;
  }
  __syncthreads();
  return v + (wid ? wsum[wid - 1] : 0);
}

// ---------- per-bucket CSR build: local bucket-base scan,
// contiguous ~50 KB stage read, full-width phases ----------
__global__ __launch_bounds__(256) void csr_build(
    const unsigned* __restrict__ part, const int* __restrict__ countsT,
    const int* __restrict__ btot,
    int* __restrict__ csr0, int* __restrict__ csr1, int* __restrict__ csr2,
    int* __restrict__ rp0, int* __restrict__ rp1, int* __restrict__ rp2) {
  __shared__ int segcnt[256];
  __shared__ int segoff[256];
  __shared__ int wsum[4];
  __shared__ int nTot;
  __shared__ int sBase;
  __shared__ unsigned stage[BUKCAP];     // 16 KB
  __shared__ int cnt[256];
  __shared__ int curs[256];
  __shared__ unsigned short img[BUKCAP]; // 8 KB
  int blk = blockIdx.x;
  int rel = blk / NBUK, lb = blk - rel * NBUK;
  int* __restrict__ csr = (rel == 0) ? csr0 : (rel == 1) ? csr1 : csr2;
  int* __restrict__ rp  = (rel == 0) ? rp0  : (rel == 1) ? rp1  : rp2;
  int t = threadIdx.x;

  // bucket base: local exclusive scan over this rel's 196 bucket totals
  int c = (t < KPART) ? countsT[(size_t)blk * KPART + t] : 0;  // issue early
  int bt = (t < NBUK) ? btot[rel * NBUK + t] : 0;
  int cB = min(bt, BUKCAP);
  int inclB = block_scan_incl(cB, wsum);
  if (t == lb) sBase = inclB - cB;
  if (lb == 0 && t == 0) rp[N_NODES] = NEDGE;
  __syncthreads();
  int base = sBase;

  // per-segment counts -> packed offsets
  int incl = block_scan_incl(c, wsum);
  segcnt[t] = c;
  segoff[t] = incl - c;
  if (t == 255) nTot = incl;
  __syncthreads();
  int n = min(nTot, BUKCAP);

  // Phase A: coalesced read of the bucket's contiguous region, compact into stage
  const unsigned* __restrict__ reg = part + (size_t)blk * KPART * SEGCAP;
  for (int i = t; i < KPART * SEGCAP; i += 256) {
    int k = i / SEGCAP, j = i - k * SEGCAP;
    if (j < segcnt[k]) stage[segoff[k] + j] = reg[i];
  }
  cnt[t] = 0;
  __syncthreads();

  // Phase B: per-dst counts over stage
  for (int i = t; i < n; i += 256)
    atomicAdd(&cnt[(stage[i] >> 16) & 255], 1);
  __syncthreads();
  int c2 = cnt[t];
  int incl2 = block_scan_incl(c2, wsum);
  int excl2 = incl2 - c2;
  curs[t] = excl2;
  int d = lb * 256 + t;
  if (d < N_NODES) rp[d] = base + excl2;
  __syncthreads();

  // Phase C: place into img, dump coalesced
  for (int i = t; i < n; i += 256) {
    unsigned en = stage[i];
    int pos = atomicAdd(&curs[(en >> 16) & 255], 1);
    img[pos] = (unsigned short)(en & 0xffffu);
  }
  __syncthreads();
  for (int i = t; i < n; i += 256)
    csr[base + i] = (int)img[i];
}

// ---------- gather-mean aggregation, column-chunked by XCD parity ----------
// Each wave aggregates one (dst row, 64-col chunk). chunk = blockIdx & 1, so
// under round-robin blockIdx->XCD dispatch, even XCDs only touch cols 0-63
// and odd XCDs cols 64-127: per-XCD x-footprint halves to 6.4 MB -> higher
// L2 hit rate -> less L2-miss-path traffic (the measured bottleneck).
// 8 lanes x 16 B = one 128-B line per gather; 8 edge slots/wave, 2x unrolled.
__global__ __launch_bounds__(256) void agg_all(
    const unsigned short* __restrict__ xu_b, const unsigned short* __restrict__ xi_b,
    const int* __restrict__ rp0, const int* __restrict__ rp1, const int* __restrict__ rp2,
    const int* __restrict__ csr0, const int* __restrict__ csr1, const int* __restrict__ csr2,
    unsigned short* __restrict__ aggF, unsigned short* __restrict__ aggBB,
    unsigned short* __restrict__ aggB) {
  int rel = blockIdx.x / 25000;
  int blk = blockIdx.x - rel * 25000;
  int chunk = blk & 1;                 // rel*25000 % 8 == 0 -> chunk == blockIdx&1
  int rblk = blk >> 1;                 // 12500 row-blocks of 4 rows
  const unsigned short* x = (rel == 1) ? xi_b : xu_b;
  const int* rp  = (rel == 0) ? rp0  : (rel == 1) ? rp1  : rp2;
  const int* csr = (rel == 0) ? csr0 : (rel == 1) ? csr1 : csr2;
  unsigned short* agg = (rel == 0) ? aggF : (rel == 1) ? aggBB : aggB;

  int w = rblk * 4 + ((int)threadIdx.x >> 6);    // dst row, one wave per (row,chunk)
  int lane = threadIdx.x & 63;
  int sub = lane & 7, slot = lane >> 3;          // 8 lanes x 16 B = 128 B chunk
  int cb = chunk * 8;                            // col offset in uint4 units
  const uint4* __restrict__ xv = (const uint4*)x;
  int beg = rp[w], end = rp[w + 1];
  float a0 = 0, a1 = 0, a2 = 0, a3 = 0, a4 = 0, a5 = 0, a6 = 0, a7 = 0;
#define ACC8(v) { \
    a0 += bflo(v.x); a1 += bfhi(v.x); \
    a2 += bflo(v.y); a3 += bfhi(v.y); \
    a4 += bflo(v.z); a5 += bfhi(v.z); \
    a6 += bflo(v.w); a7 += bfhi(v.w); }
  for (int e = beg + slot; e < end; e += 16) {
    int i0 = csr[e];
    uint4 v0 = xv[(size_t)i0 * 16 + cb + sub];
    if (e + 8 < end) {
      int i1 = csr[e + 8];
      uint4 v1 = xv[(size_t)i1 * 16 + cb + sub];
      ACC8(v1);
    }
    ACC8(v0);
  }
#undef ACC8
  // reduce across the 8 slots (lane bits 3..5)
#define REDSLOT(a) { a += __shfl_xor(a, 8, 64); a += __shfl_xor(a, 16, 64); \
                     a += __shfl_xor(a, 32, 64); }
  REDSLOT(a0) REDSLOT(a1) REDSLOT(a2) REDSLOT(a3)
  REDSLOT(a4) REDSLOT(a5) REDSLOT(a6) REDSLOT(a7)
#undef REDSLOT
  if (slot == 0) {
    float rd = 1.0f / fmaxf((float)(end - beg), 1.0f);
    uint4 o;
    o.x = (unsigned)f2bf(a0 * rd) | ((unsigned)f2bf(a1 * rd) << 16);
    o.y = (unsigned)f2bf(a2 * rd) | ((unsigned)f2bf(a3 * rd) << 16);
    o.z = (unsigned)f2bf(a4 * rd) | ((unsigned)f2bf(a5 * rd) << 16);
    o.w = (unsigned)f2bf(a6 * rd) | ((unsigned)f2bf(a7 * rd) << 16);
    ((uint4*)agg)[(size_t)w * 16 + cb + sub] = o;
  }
}

// ---------- MFMA GEMM: out = relu(sum_s A_s @ W_s + bias), both halves ----------
__global__ __launch_bounds__(256) void mfma_gemm(
    const unsigned short* __restrict__ aggF, const unsigned short* __restrict__ aggBB,
    const unsigned short* __restrict__ aggB,
    const unsigned short* __restrict__ xu, const unsigned short* __restrict__ xi,
    const unsigned short* __restrict__ wfrag,
    const float* __restrict__ b_lu, const float* __restrict__ b_li,
    float* __restrict__ out) {
  __shared__ unsigned short As[8192];   // [rt(4)][kc(4)][lane(64)][8]
  const int t = threadIdx.x;
  const int b = blockIdx.x;
  const int half = (b >= BLK_PER_HALF) ? 1 : 0;
  const int g0 = (half ? b - BLK_PER_HALF : b) * 64;
  const int lane = t & 63;
  const int w = t >> 6;
  const int nsrc = half ? 2 : 3;
  const int widx0 = half ? 3 : 0;

  const unsigned short* A0 = half ? aggB : aggF;
  const unsigned short* A1 = half ? xi   : aggBB;
  const unsigned short* A2 = xu;

  f32x4 acc[4][2] = {};

  for (int s = 0; s < nsrc; ++s) {
    const unsigned short* A = (s == 0) ? A0 : (s == 1) ? A1 : A2;
#pragma unroll
    for (int i = 0; i < 4; ++i) {
      int idx = t + i * 256;
      int row = idx >> 4;
      int c8 = (idx & 15) << 3;
      int gr = g0 + row;
      float4 v = make_float4(0.f, 0.f, 0.f, 0.f);
      if (gr < N_NODES)
        v = *reinterpret_cast<const float4*>(A + (size_t)gr * FEAT + c8);
      int rt = row >> 4, m = row & 15;
      int kc = c8 >> 5, q = (c8 >> 3) & 3;
      *reinterpret_cast<float4*>(&As[((rt * 4 + kc) * 64 + (q * 16 + m)) * 8]) = v;
    }
    __syncthreads();
    const unsigned short* wf = wfrag + (size_t)(widx0 + s) * (4 * 8 * 64 * 8);
#pragma unroll
    for (int kc = 0; kc < 4; ++kc) {
      short8 bfr[2];
#pragma unroll
      for (int ct = 0; ct < 2; ++ct) {
        int nt = 2 * w + ct;
        bfr[ct] = *reinterpret_cast<const short8*>(wf + ((kc * 8 + nt) * 64 + lane) * 8);
      }
#pragma unroll
      for (int rt = 0; rt < 4; ++rt) {
        short8 afr = *reinterpret_cast<const short8*>(&As[((rt * 4 + kc) * 64 + lane) * 8]);
#pragma unroll
        for (int ct = 0; ct < 2; ++ct)
          acc[rt][ct] = __builtin_amdgcn_mfma_f32_16x16x32_bf16(afr, bfr[ct],
                                                                acc[rt][ct], 0, 0, 0);
      }
    }
    __syncthreads();
  }

  const float* bias = half ? b_li : b_lu;
  int q = lane >> 4, nl = lane & 15;
  float bv[2] = { bias[w * 32 + nl], bias[w * 32 + 16 + nl] };
#pragma unroll
  for (int rt = 0; rt < 4; ++rt)
#pragma unroll
    for (int r = 0; r < 4; ++r) {
      int gr = g0 + rt * 16 + q * 4 + r;
      if (gr < N_NODES) {
        size_t orow = (size_t)(half ? N_NODES : 0) + gr;
#pragma unroll
        for (int ct = 0; ct < 2; ++ct) {
          float v = acc[rt][ct][r] + bv[ct];
          out[orow * FEAT + w * 32 + ct * 16 + nl] = fmaxf(v, 0.f);
        }
      }
    }
}

extern "C" void kernel_launch(void* const* d_in, const int* in_sizes, int n_in,
                              void* d_out, int out_size, void* d_ws, size_t ws_size,
                              hipStream_t stream) {
  const float* x_user = (const float*)d_in[0];
  const float* x_item = (const float*)d_in[1];
  const void* e_fol = d_in[2];
  const void* e_buy = d_in[3];
  const void* e_bb  = d_in[4];
  const float* W_fol = (const float*)d_in[5];
  const float* W_buy = (const float*)d_in[6];
  const float* W_bb  = (const float*)d_in[7];
  const float* W_lu  = (const float*)d_in[8];
  const float* b_lu  = (const float*)d_in[9];
  const float* W_li  = (const float*)d_in[10];
  const float* b_li  = (const float*)d_in[11];
  float* out = (float*)d_out;

  // ws: bf16 arrays (64.16 MB) then ints (~8.4 MB). part (29.5 MB) ALIASES
  // aggF/aggBB/aggB (38.4 MB) -- part is dead before agg_all writes them.
  unsigned short* wsu = (unsigned short*)d_ws;
  unsigned short* aggF  = wsu;
  unsigned short* aggBB = wsu + 6400000;
  unsigned short* aggB  = wsu + 12800000;
  unsigned short* xu_b  = wsu + 19200000;
  unsigned short* xi_b  = wsu + 25600000;
  unsigned short* wfrag = wsu + 32000000;      // 81920 ushorts
  unsigned* part = (unsigned*)d_ws;            // NBUKT*KPART*SEGCAP = 7,375,368 uints
  int* ip = (int*)d_ws + 16040960;
  int* csr0 = ip;
  int* csr1 = ip + 600000;
  int* csr2 = ip + 1200000;
  int* rp0  = ip + 1800000;     // 50016 each
  int* rp1  = rp0 + 50016;
  int* rp2  = rp1 + 50016;
  int* countsT = ip + 1950048;  // NBUKT*KPART = 131712
  int* btot    = ip + 2081760;  // 588

  // zero the cross-block bucket totals (graph-capturable)
  hipMemsetAsync(btot, 0, NBUKT * sizeof(int), stream);

  part_cvt<<<KPART + NB_CVT + NB_W, 256, 0, stream>>>(
      e_fol, e_bb, e_buy, part, countsT, btot, x_user, x_item,
      W_fol, W_bb, W_lu, W_buy, W_li, xu_b, xi_b, wfrag);

  csr_build<<<3 * NBUK, 256, 0, stream>>>(part, countsT, btot,
                                          csr0, csr1, csr2, rp0, rp1, rp2);

  agg_all<<<3 * 25000, 256, 0, stream>>>(xu_b, xi_b, rp0, rp1, rp2,
                                         csr0, csr1, csr2, aggF, aggBB, aggB);

  mfma_gemm<<<2 * BLK_PER_HALF, 256, 0, stream>>>(
      aggF, aggBB, aggB, xu_b, xi_b, wfrag, b_lu, b_li, out);
}

// Round 6
// 268.780 us; speedup vs baseline: 1.1097x; 1.1097x over previous
//
#include <hip/hip_runtime.h>

#define N_NODES 50000
#define FEAT    128
#define NEDGE   600000
#define BLK_PER_HALF 782   // ceil(50000/64)

#define NBUK    196        // buckets per rel (256 dsts each); 588 total
#define NBUKT   588
#define BUKCAP  4096       // bucket total: mean 3061, sigma 55 -> 19 sigma
#define KPART   224        // partition blocks
#define SEGCAP  56         // mean 13.7, Poisson tail @56 ~ 1e-16/segment
#define SEGQ    14         // SEGCAP/4 uint4s
#define EPB     2679       // ceil(600000/224)
#define NB_CVT  6250       // 2 x 3125
#define NB_W    5

typedef __attribute__((ext_vector_type(8))) short short8;
typedef __attribute__((ext_vector_type(4))) float f32x4;

// ---------- bf16 helpers ----------
__device__ __forceinline__ unsigned short f2bf(float f) {
  unsigned u = __float_as_uint(f);
  return (unsigned short)((u + 0x7fffu + ((u >> 16) & 1u)) >> 16);
}
__device__ __forceinline__ float bflo(unsigned u) { return __uint_as_float(u << 16); }
__device__ __forceinline__ float bfhi(unsigned u) { return __uint_as_float(u & 0xffff0000u); }

__device__ __forceinline__ int edge_at(const void* __restrict__ edges, long i, int is64) {
  return is64 ? (int)((const long long*)edges)[i] : ((const int*)edges)[i];
}

// ---------- fused: LDS-staged partition + x->bf16 conversion + W pack ----------
// Partition: per-rel passes; segments staged in LDS (no scattered global
// stores in the hot loop), flushed as contiguous 224-B uint4 runs.
// part layout TRANSPOSED: part[(bucket*KPART + block)*SEGCAP + pos]
// -> a bucket's 224 segments are one contiguous ~50 KB region for csr_build.
__global__ __launch_bounds__(256) void part_cvt(
    const void* __restrict__ e0, const void* __restrict__ e1, const void* __restrict__ e2,
    unsigned* __restrict__ part, int* __restrict__ countsT, int* __restrict__ btot,
    const float* __restrict__ xu, const float* __restrict__ xi,
    const float* __restrict__ W_fol, const float* __restrict__ W_bb,
    const float* __restrict__ W_lu, const float* __restrict__ W_buy,
    const float* __restrict__ W_li,
    unsigned short* __restrict__ xu_b, unsigned short* __restrict__ xi_b,
    unsigned short* __restrict__ wfrag) {
  __shared__ unsigned stg[NBUK * SEGCAP];   // 43904 B staging
  __shared__ int scnt[NBUK];
  __shared__ int s_is64;
  int b = blockIdx.x;
  int t = threadIdx.x;
  if (b < KPART) {
    // inline dtype detect: wave 0 samples the first 64 u32-pair hi words
    if (t < 64) {
      unsigned hi = ((const unsigned*)e0)[2 * t + 1];
      unsigned long long any = __ballot(hi != 0u);
      if (t == 0) s_is64 = (any == 0ull) ? 1 : 0;
    }
    __syncthreads();
    int is64 = s_is64;
    const void* es[3] = {e0, e1, e2};
    int ebase = b * EPB;
    int eend = min(ebase + EPB, NEDGE);
    for (int rel = 0; rel < 3; ++rel) {
      for (int i = t; i < NBUK; i += 256) scnt[i] = 0;
      __syncthreads();
      const void* ep = es[rel];
      for (int ei = ebase + t; ei < eend; ei += 256) {
        int src = edge_at(ep, ei, is64);
        int dst = edge_at(ep, (long)NEDGE + ei, is64);
        int bk = dst >> 8;
        int pos = atomicAdd(&scnt[bk], 1);
        if (pos < SEGCAP)
          stg[bk * SEGCAP + pos] = (unsigned)src | ((unsigned)(dst & 255) << 16);
      }
      __syncthreads();
      // coalesced flush: full segments (stale tail entries bounded by countsT)
      const uint4* s4 = (const uint4*)stg;
      uint4* p4 = (uint4*)part;
      for (int i = t; i < NBUK * SEGQ; i += 256) {
        int bk = i / SEGQ, j = i - bk * SEGQ;
        p4[((size_t)((rel * NBUK + bk) * KPART + b)) * SEGQ + j] = s4[i];
      }
      for (int i = t; i < NBUK; i += 256) {
        int c = min(scnt[i], SEGCAP);
        countsT[(rel * NBUK + i) * KPART + b] = c;
        atomicAdd(&btot[rel * NBUK + i], c);   // cross-block totals (pre-zeroed)
      }
      __syncthreads();   // before reusing scnt/stg for next rel
    }
  } else if (b < KPART + NB_CVT) {
    int cb = b - KPART;
    const float* src = (cb < 3125) ? xu : xi;
    unsigned short* dst = (cb < 3125) ? xu_b : xi_b;
    int lb = (cb < 3125) ? cb : cb - 3125;
    size_t base = ((size_t)lb * 256 + t) * 8;
    float4 v0 = *reinterpret_cast<const float4*>(src + base);
    float4 v1 = *reinterpret_cast<const float4*>(src + base + 4);
    uint4 o;
    o.x = f2bf(v0.x) | ((unsigned)f2bf(v0.y) << 16);
    o.y = f2bf(v0.z) | ((unsigned)f2bf(v0.w) << 16);
    o.z = f2bf(v1.x) | ((unsigned)f2bf(v1.y) << 16);
    o.w = f2bf(v1.z) | ((unsigned)f2bf(v1.w) << 16);
    *reinterpret_cast<uint4*>(dst + base) = o;
  } else {
    int s = b - (KPART + NB_CVT);
    const float* W = (s == 0) ? W_fol : (s == 1) ? W_bb : (s == 2) ? W_lu
                    : (s == 3) ? W_buy : W_li;
    for (int idx = t; idx < 16384; idx += 256) {
      int k = idx >> 7, n = idx & 127;
      int kc = k >> 5, q = (k >> 3) & 3, j = k & 7;
      int nt = n >> 4, nl = n & 15;
      wfrag[((((size_t)s * 4 + kc) * 8 + nt) * 64 + (q * 16 + nl)) * 8 + j] = f2bf(W[idx]);
    }
  }
}

// ---------- block scan helper ----------
__device__ __forceinline__ int block_scan_incl(int v, int* wsum) {
  int lane = threadIdx.x & 63, wid = threadIdx.x >> 6;
#pragma unroll
  for (int d = 1; d < 64; d <<= 1) {
    int n = __shfl_up(v, d, 64);
    if (lane >= d) v += n;
  }
  if (lane == 63) wsum[wid] = v;
  __syncthreads();
  if (threadIdx.x < 4) {
    int s = wsum[threadIdx.x];
#pragma unroll
    for (int d = 1; d < 4; d <<= 1) {
      int n = __shfl_up(s, d, 64);
      if ((int)threadIdx.x >= d) s += n;
    }
    wsum[threadIdx.x] = s;
  }
  __syncthreads();
  return v + (wid ? wsum[wid - 1] : 0);
}

// ---------- per-bucket CSR build: local bucket-base scan,
// contiguous ~50 KB stage read, full-width phases ----------
__global__ __launch_bounds__(256) void csr_build(
    const unsigned* __restrict__ part, const int* __restrict__ countsT,
    const int* __restrict__ btot,
    int* __restrict__ csr0, int* __restrict__ csr1, int* __restrict__ csr2,
    int* __restrict__ rp0, int* __restrict__ rp1, int* __restrict__ rp2) {
  __shared__ int segcnt[256];
  __shared__ int segoff[256];
  __shared__ int wsum[4];
  __shared__ int nTot;
  __shared__ int sBase;
  __shared__ unsigned stage[BUKCAP];     // 16 KB
  __shared__ int cnt[256];
  __shared__ int curs[256];
  __shared__ unsigned short img[BUKCAP]; // 8 KB
  int blk = blockIdx.x;
  int rel = blk / NBUK, lb = blk - rel * NBUK;
  int* __restrict__ csr = (rel == 0) ? csr0 : (rel == 1) ? csr1 : csr2;
  int* __restrict__ rp  = (rel == 0) ? rp0  : (rel == 1) ? rp1  : rp2;
  int t = threadIdx.x;

  // bucket base: local exclusive scan over this rel's 196 bucket totals
  int c = (t < KPART) ? countsT[(size_t)blk * KPART + t] : 0;  // issue early
  int bt = (t < NBUK) ? btot[rel * NBUK + t] : 0;
  int cB = min(bt, BUKCAP);
  int inclB = block_scan_incl(cB, wsum);
  if (t == lb) sBase = inclB - cB;
  if (lb == 0 && t == 0) rp[N_NODES] = NEDGE;
  __syncthreads();
  int base = sBase;

  // per-segment counts -> packed offsets
  int incl = block_scan_incl(c, wsum);
  segcnt[t] = c;
  segoff[t] = incl - c;
  if (t == 255) nTot = incl;
  __syncthreads();
  int n = min(nTot, BUKCAP);

  // Phase A: coalesced read of the bucket's contiguous region, compact into stage
  const unsigned* __restrict__ reg = part + (size_t)blk * KPART * SEGCAP;
  for (int i = t; i < KPART * SEGCAP; i += 256) {
    int k = i / SEGCAP, j = i - k * SEGCAP;
    if (j < segcnt[k]) stage[segoff[k] + j] = reg[i];
  }
  cnt[t] = 0;
  __syncthreads();

  // Phase B: per-dst counts over stage
  for (int i = t; i < n; i += 256)
    atomicAdd(&cnt[(stage[i] >> 16) & 255], 1);
  __syncthreads();
  int c2 = cnt[t];
  int incl2 = block_scan_incl(c2, wsum);
  int excl2 = incl2 - c2;
  curs[t] = excl2;
  int d = lb * 256 + t;
  if (d < N_NODES) rp[d] = base + excl2;
  __syncthreads();

  // Phase C: place into img, dump coalesced
  for (int i = t; i < n; i += 256) {
    unsigned en = stage[i];
    int pos = atomicAdd(&curs[(en >> 16) & 255], 1);
    img[pos] = (unsigned short)(en & 0xffffu);
  }
  __syncthreads();
  for (int i = t; i < n; i += 256)
    csr[base + i] = (int)img[i];
}

// ---------- gather-mean aggregation: 2 rows x 1 chunk per wave ----------
// Footprint halving (R5's XCD-parity chunking: even XCDs read cols 0-63,
// odd XCDs cols 64-127 -> 6.4 MB/XCD L2 footprint, FETCH 176->130 MB) at
// R4's wave economics (150k waves total, same gather bytes/instr, same
// ACC8-per-byte). Wave: lanes 0-31 row A, lanes 32-63 row B; within a half
// 8 lanes x 16 B = one 128-B line, 4 edge slots, 4-deep predicated unroll.
__global__ __launch_bounds__(256) void agg_all(
    const unsigned short* __restrict__ xu_b, const unsigned short* __restrict__ xi_b,
    const int* __restrict__ rp0, const int* __restrict__ rp1, const int* __restrict__ rp2,
    const int* __restrict__ csr0, const int* __restrict__ csr1, const int* __restrict__ csr2,
    unsigned short* __restrict__ aggF, unsigned short* __restrict__ aggBB,
    unsigned short* __restrict__ aggB) {
  int rel = blockIdx.x / 12500;
  int blk = blockIdx.x - rel * 12500;
  int chunk = blk & 1;                 // 12500 even -> chunk tracks blockIdx&1 (XCD parity)
  int rblk = blk >> 1;                 // 6250 row-blocks of 8 rows
  const unsigned short* x = (rel == 1) ? xi_b : xu_b;
  const int* rp  = (rel == 0) ? rp0  : (rel == 1) ? rp1  : rp2;
  const int* csr = (rel == 0) ? csr0 : (rel == 1) ? csr1 : csr2;
  unsigned short* agg = (rel == 0) ? aggF : (rel == 1) ? aggBB : aggB;

  int wid = (int)threadIdx.x >> 6;
  int lane = threadIdx.x & 63;
  int half = lane >> 5;                // which row within the wave
  int l32 = lane & 31;
  int sub = l32 & 7;                   // 16-B slice of the 128-B chunk line
  int slot = l32 >> 3;                 // 4 edge slots per row
  int w = rblk * 8 + wid * 2 + half;   // dst row (50000 = 6250*8 exact)
  int cb = chunk * 8;                  // col offset in uint4 units
  const uint4* __restrict__ xv = (const uint4*)x;
  int beg = rp[w], end = rp[w + 1];
  float a0 = 0, a1 = 0, a2 = 0, a3 = 0, a4 = 0, a5 = 0, a6 = 0, a7 = 0;
#define ACC8(v) { \
    a0 += bflo(v.x); a1 += bfhi(v.x); \
    a2 += bflo(v.y); a3 += bfhi(v.y); \
    a4 += bflo(v.z); a5 += bfhi(v.z); \
    a6 += bflo(v.w); a7 += bfhi(v.w); }
  for (int e = beg + slot; e < end; e += 16) {
    int i0 = csr[e];
    uint4 v0 = xv[(size_t)i0 * 16 + cb + sub];
    if (e + 4 < end) {
      int i1 = csr[e + 4];
      uint4 v1 = xv[(size_t)i1 * 16 + cb + sub];
      if (e + 8 < end) {
        int i2 = csr[e + 8];
        uint4 v2 = xv[(size_t)i2 * 16 + cb + sub];
        if (e + 12 < end) {
          int i3 = csr[e + 12];
          uint4 v3 = xv[(size_t)i3 * 16 + cb + sub];
          ACC8(v3);
        }
        ACC8(v2);
      }
      ACC8(v1);
    }
    ACC8(v0);
  }
#undef ACC8
  // reduce across the 4 slots (lane bits 3,4) -- stays within each 32-lane half
#define REDSLOT(a) { a += __shfl_xor(a, 8, 64); a += __shfl_xor(a, 16, 64); }
  REDSLOT(a0) REDSLOT(a1) REDSLOT(a2) REDSLOT(a3)
  REDSLOT(a4) REDSLOT(a5) REDSLOT(a6) REDSLOT(a7)
#undef REDSLOT
  if (slot == 0) {                     // lanes 0-7 (row A) and 32-39 (row B)
    float rd = 1.0f / fmaxf((float)(end - beg), 1.0f);
    uint4 o;
    o.x = (unsigned)f2bf(a0 * rd) | ((unsigned)f2bf(a1 * rd) << 16);
    o.y = (unsigned)f2bf(a2 * rd) | ((unsigned)f2bf(a3 * rd) << 16);
    o.z = (unsigned)f2bf(a4 * rd) | ((unsigned)f2bf(a5 * rd) << 16);
    o.w = (unsigned)f2bf(a6 * rd) | ((unsigned)f2bf(a7 * rd) << 16);
    ((uint4*)agg)[(size_t)w * 16 + cb + sub] = o;
  }
}

// ---------- MFMA GEMM: out = relu(sum_s A_s @ W_s + bias), both halves ----------
__global__ __launch_bounds__(256) void mfma_gemm(
    const unsigned short* __restrict__ aggF, const unsigned short* __restrict__ aggBB,
    const unsigned short* __restrict__ aggB,
    const unsigned short* __restrict__ xu, const unsigned short* __restrict__ xi,
    const unsigned short* __restrict__ wfrag,
    const float* __restrict__ b_lu, const float* __restrict__ b_li,
    float* __restrict__ out) {
  __shared__ unsigned short As[8192];   // [rt(4)][kc(4)][lane(64)][8]
  const int t = threadIdx.x;
  const int b = blockIdx.x;
  const int half = (b >= BLK_PER_HALF) ? 1 : 0;
  const int g0 = (half ? b - BLK_PER_HALF : b) * 64;
  const int lane = t & 63;
  const int w = t >> 6;
  const int nsrc = half ? 2 : 3;
  const int widx0 = half ? 3 : 0;

  const unsigned short* A0 = half ? aggB : aggF;
  const unsigned short* A1 = half ? xi   : aggBB;
  const unsigned short* A2 = xu;

  f32x4 acc[4][2] = {};

  for (int s = 0; s < nsrc; ++s) {
    const unsigned short* A = (s == 0) ? A0 : (s == 1) ? A1 : A2;
#pragma unroll
    for (int i = 0; i < 4; ++i) {
      int idx = t + i * 256;
      int row = idx >> 4;
      int c8 = (idx & 15) << 3;
      int gr = g0 + row;
      float4 v = make_float4(0.f, 0.f, 0.f, 0.f);
      if (gr < N_NODES)
        v = *reinterpret_cast<const float4*>(A + (size_t)gr * FEAT + c8);
      int rt = row >> 4, m = row & 15;
      int kc = c8 >> 5, q = (c8 >> 3) & 3;
      *reinterpret_cast<float4*>(&As[((rt * 4 + kc) * 64 + (q * 16 + m)) * 8]) = v;
    }
    __syncthreads();
    const unsigned short* wf = wfrag + (size_t)(widx0 + s) * (4 * 8 * 64 * 8);
#pragma unroll
    for (int kc = 0; kc < 4; ++kc) {
      short8 bfr[2];
#pragma unroll
      for (int ct = 0; ct < 2; ++ct) {
        int nt = 2 * w + ct;
        bfr[ct] = *reinterpret_cast<const short8*>(wf + ((kc * 8 + nt) * 64 + lane) * 8);
      }
#pragma unroll
      for (int rt = 0; rt < 4; ++rt) {
        short8 afr = *reinterpret_cast<const short8*>(&As[((rt * 4 + kc) * 64 + lane) * 8]);
#pragma unroll
        for (int ct = 0; ct < 2; ++ct)
          acc[rt][ct] = __builtin_amdgcn_mfma_f32_16x16x32_bf16(afr, bfr[ct],
                                                                acc[rt][ct], 0, 0, 0);
      }
    }
    __syncthreads();
  }

  const float* bias = half ? b_li : b_lu;
  int q = lane >> 4, nl = lane & 15;
  float bv[2] = { bias[w * 32 + nl], bias[w * 32 + 16 + nl] };
#pragma unroll
  for (int rt = 0; rt < 4; ++rt)
#pragma unroll
    for (int r = 0; r < 4; ++r) {
      int gr = g0 + rt * 16 + q * 4 + r;
      if (gr < N_NODES) {
        size_t orow = (size_t)(half ? N_NODES : 0) + gr;
#pragma unroll
        for (int ct = 0; ct < 2; ++ct) {
          float v = acc[rt][ct][r] + bv[ct];
          out[orow * FEAT + w * 32 + ct * 16 + nl] = fmaxf(v, 0.f);
        }
      }
    }
}

extern "C" void kernel_launch(void* const* d_in, const int* in_sizes, int n_in,
                              void* d_out, int out_size, void* d_ws, size_t ws_size,
                              hipStream_t stream) {
  const float* x_user = (const float*)d_in[0];
  const float* x_item = (const float*)d_in[1];
  const void* e_fol = d_in[2];
  const void* e_buy = d_in[3];
  const void* e_bb  = d_in[4];
  const float* W_fol = (const float*)d_in[5];
  const float* W_buy = (const float*)d_in[6];
  const float* W_bb  = (const float*)d_in[7];
  const float* W_lu  = (const float*)d_in[8];
  const float* b_lu  = (const float*)d_in[9];
  const float* W_li  = (const float*)d_in[10];
  const float* b_li  = (const float*)d_in[11];
  float* out = (float*)d_out;

  // ws: bf16 arrays (64.16 MB) then ints (~8.4 MB). part (29.5 MB) ALIASES
  // aggF/aggBB/aggB (38.4 MB) -- part is dead before agg_all writes them.
  unsigned short* wsu = (unsigned short*)d_ws;
  unsigned short* aggF  = wsu;
  unsigned short* aggBB = wsu + 6400000;
  unsigned short* aggB  = wsu + 12800000;
  unsigned short* xu_b  = wsu + 19200000;
  unsigned short* xi_b  = wsu + 25600000;
  unsigned short* wfrag = wsu + 32000000;      // 81920 ushorts
  unsigned* part = (unsigned*)d_ws;            // NBUKT*KPART*SEGCAP = 7,375,368 uints
  int* ip = (int*)d_ws + 16040960;
  int* csr0 = ip;
  int* csr1 = ip + 600000;
  int* csr2 = ip + 1200000;
  int* rp0  = ip + 1800000;     // 50016 each
  int* rp1  = rp0 + 50016;
  int* rp2  = rp1 + 50016;
  int* countsT = ip + 1950048;  // NBUKT*KPART = 131712
  int* btot    = ip + 2081760;  // 588

  // zero the cross-block bucket totals (graph-capturable)
  hipMemsetAsync(btot, 0, NBUKT * sizeof(int), stream);

  part_cvt<<<KPART + NB_CVT + NB_W, 256, 0, stream>>>(
      e_fol, e_bb, e_buy, part, countsT, btot, x_user, x_item,
      W_fol, W_bb, W_lu, W_buy, W_li, xu_b, xi_b, wfrag);

  csr_build<<<3 * NBUK, 256, 0, stream>>>(part, countsT, btot,
                                          csr0, csr1, csr2, rp0, rp1, rp2);

  agg_all<<<3 * 12500, 256, 0, stream>>>(xu_b, xi_b, rp0, rp1, rp2,
                                         csr0, csr1, csr2, aggF, aggBB, aggB);

  mfma_gemm<<<2 * BLK_PER_HALF, 256, 0, stream>>>(
      aggF, aggBB, aggB, xu_b, xi_b, wfrag, b_lu, b_li, out);
}

// Round 7
// 257.617 us; speedup vs baseline: 1.1578x; 1.0433x over previous
//
#include <hip/hip_runtime.h>

#define N_NODES 50000
#define FEAT    128
#define NEDGE   600000

#define NBUK    196        // buckets per rel (256 dsts each); 588 total
#define NBUKT   588
#define BUKCAP  4096       // bucket total: mean 3061, sigma 55 -> 19 sigma
#define KPART   224        // partition blocks
#define SEGCAP  56         // mean 13.7, Poisson tail @56 ~ 1e-16/segment
#define SEGQ    14         // SEGCAP/4 uint4s
#define EPB     2679       // ceil(600000/224)
#define NB_CVT  6250       // 2 x 3125
#define NB_W    5

#define TBLK    3125       // 16-row tiles per half (50000/16 exact)
#define LDA     136        // padded LDS row stride (ushorts); 272 B = 17*16, 16B-aligned

typedef __attribute__((ext_vector_type(8))) short short8;
typedef __attribute__((ext_vector_type(4))) float f32x4;

// ---------- bf16 helpers ----------
__device__ __forceinline__ unsigned short f2bf(float f) {
  unsigned u = __float_as_uint(f);
  return (unsigned short)((u + 0x7fffu + ((u >> 16) & 1u)) >> 16);
}
__device__ __forceinline__ float bflo(unsigned u) { return __uint_as_float(u << 16); }
__device__ __forceinline__ float bfhi(unsigned u) { return __uint_as_float(u & 0xffff0000u); }

__device__ __forceinline__ int edge_at(const void* __restrict__ edges, long i, int is64) {
  return is64 ? (int)((const long long*)edges)[i] : ((const int*)edges)[i];
}

// ---------- fused: LDS-staged partition + x->bf16 conversion + W pack ----------
__global__ __launch_bounds__(256) void part_cvt(
    const void* __restrict__ e0, const void* __restrict__ e1, const void* __restrict__ e2,
    unsigned* __restrict__ part, int* __restrict__ countsT, int* __restrict__ btot,
    const float* __restrict__ xu, const float* __restrict__ xi,
    const float* __restrict__ W_fol, const float* __restrict__ W_bb,
    const float* __restrict__ W_lu, const float* __restrict__ W_buy,
    const float* __restrict__ W_li,
    unsigned short* __restrict__ xu_b, unsigned short* __restrict__ xi_b,
    unsigned short* __restrict__ wfrag) {
  __shared__ unsigned stg[NBUK * SEGCAP];   // 43904 B staging
  __shared__ int scnt[NBUK];
  __shared__ int s_is64;
  int b = blockIdx.x;
  int t = threadIdx.x;
  if (b < KPART) {
    if (t < 64) {
      unsigned hi = ((const unsigned*)e0)[2 * t + 1];
      unsigned long long any = __ballot(hi != 0u);
      if (t == 0) s_is64 = (any == 0ull) ? 1 : 0;
    }
    __syncthreads();
    int is64 = s_is64;
    const void* es[3] = {e0, e1, e2};
    int ebase = b * EPB;
    int eend = min(ebase + EPB, NEDGE);
    for (int rel = 0; rel < 3; ++rel) {
      for (int i = t; i < NBUK; i += 256) scnt[i] = 0;
      __syncthreads();
      const void* ep = es[rel];
      for (int ei = ebase + t; ei < eend; ei += 256) {
        int src = edge_at(ep, ei, is64);
        int dst = edge_at(ep, (long)NEDGE + ei, is64);
        int bk = dst >> 8;
        int pos = atomicAdd(&scnt[bk], 1);
        if (pos < SEGCAP)
          stg[bk * SEGCAP + pos] = (unsigned)src | ((unsigned)(dst & 255) << 16);
      }
      __syncthreads();
      const uint4* s4 = (const uint4*)stg;
      uint4* p4 = (uint4*)part;
      for (int i = t; i < NBUK * SEGQ; i += 256) {
        int bk = i / SEGQ, j = i - bk * SEGQ;
        p4[((size_t)((rel * NBUK + bk) * KPART + b)) * SEGQ + j] = s4[i];
      }
      for (int i = t; i < NBUK; i += 256) {
        int c = min(scnt[i], SEGCAP);
        countsT[(rel * NBUK + i) * KPART + b] = c;
        atomicAdd(&btot[rel * NBUK + i], c);
      }
      __syncthreads();
    }
  } else if (b < KPART + NB_CVT) {
    int cb = b - KPART;
    const float* src = (cb < 3125) ? xu : xi;
    unsigned short* dst = (cb < 3125) ? xu_b : xi_b;
    int lb = (cb < 3125) ? cb : cb - 3125;
    size_t base = ((size_t)lb * 256 + t) * 8;
    float4 v0 = *reinterpret_cast<const float4*>(src + base);
    float4 v1 = *reinterpret_cast<const float4*>(src + base + 4);
    uint4 o;
    o.x = f2bf(v0.x) | ((unsigned)f2bf(v0.y) << 16);
    o.y = f2bf(v0.z) | ((unsigned)f2bf(v0.w) << 16);
    o.z = f2bf(v1.x) | ((unsigned)f2bf(v1.y) << 16);
    o.w = f2bf(v1.z) | ((unsigned)f2bf(v1.w) << 16);
    *reinterpret_cast<uint4*>(dst + base) = o;
  } else {
    int s = b - (KPART + NB_CVT);
    const float* W = (s == 0) ? W_fol : (s == 1) ? W_bb : (s == 2) ? W_lu
                    : (s == 3) ? W_buy : W_li;
    for (int idx = t; idx < 16384; idx += 256) {
      int k = idx >> 7, n = idx & 127;
      int kc = k >> 5, q = (k >> 3) & 3, j = k & 7;
      int nt = n >> 4, nl = n & 15;
      wfrag[((((size_t)s * 4 + kc) * 8 + nt) * 64 + (q * 16 + nl)) * 8 + j] = f2bf(W[idx]);
    }
  }
}

// ---------- block scan helper ----------
__device__ __forceinline__ int block_scan_incl(int v, int* wsum) {
  int lane = threadIdx.x & 63, wid = threadIdx.x >> 6;
#pragma unroll
  for (int d = 1; d < 64; d <<= 1) {
    int n = __shfl_up(v, d, 64);
    if (lane >= d) v += n;
  }
  if (lane == 63) wsum[wid] = v;
  __syncthreads();
  if (threadIdx.x < 4) {
    int s = wsum[threadIdx.x];
#pragma unroll
    for (int d = 1; d < 4; d <<= 1) {
      int n = __shfl_up(s, d, 64);
      if ((int)threadIdx.x >= d) s += n;
    }
    wsum[threadIdx.x] = s;
  }
  __syncthreads();
  return v + (wid ? wsum[wid - 1] : 0);
}

// ---------- per-bucket CSR build ----------
__global__ __launch_bounds__(256) void csr_build(
    const unsigned* __restrict__ part, const int* __restrict__ countsT,
    const int* __restrict__ btot,
    int* __restrict__ csr0, int* __restrict__ csr1, int* __restrict__ csr2,
    int* __restrict__ rp0, int* __restrict__ rp1, int* __restrict__ rp2) {
  __shared__ int segcnt[256];
  __shared__ int segoff[256];
  __shared__ int wsum[4];
  __shared__ int nTot;
  __shared__ int sBase;
  __shared__ unsigned stage[BUKCAP];     // 16 KB
  __shared__ int cnt[256];
  __shared__ int curs[256];
  __shared__ unsigned short img[BUKCAP]; // 8 KB
  int blk = blockIdx.x;
  int rel = blk / NBUK, lb = blk - rel * NBUK;
  int* __restrict__ csr = (rel == 0) ? csr0 : (rel == 1) ? csr1 : csr2;
  int* __restrict__ rp  = (rel == 0) ? rp0  : (rel == 1) ? rp1  : rp2;
  int t = threadIdx.x;

  int c = (t < KPART) ? countsT[(size_t)blk * KPART + t] : 0;  // issue early
  int bt = (t < NBUK) ? btot[rel * NBUK + t] : 0;
  int cB = min(bt, BUKCAP);
  int inclB = block_scan_incl(cB, wsum);
  if (t == lb) sBase = inclB - cB;
  if (lb == 0 && t == 0) rp[N_NODES] = NEDGE;
  __syncthreads();
  int base = sBase;

  int incl = block_scan_incl(c, wsum);
  segcnt[t] = c;
  segoff[t] = incl - c;
  if (t == 255) nTot = incl;
  __syncthreads();
  int n = min(nTot, BUKCAP);

  const unsigned* __restrict__ reg = part + (size_t)blk * KPART * SEGCAP;
  for (int i = t; i < KPART * SEGCAP; i += 256) {
    int k = i / SEGCAP, j = i - k * SEGCAP;
    if (j < segcnt[k]) stage[segoff[k] + j] = reg[i];
  }
  cnt[t] = 0;
  __syncthreads();

  for (int i = t; i < n; i += 256)
    atomicAdd(&cnt[(stage[i] >> 16) & 255], 1);
  __syncthreads();
  int c2 = cnt[t];
  int incl2 = block_scan_incl(c2, wsum);
  int excl2 = incl2 - c2;
  curs[t] = excl2;
  int d = lb * 256 + t;
  if (d < N_NODES) rp[d] = base + excl2;
  __syncthreads();

  for (int i = t; i < n; i += 256) {
    unsigned en = stage[i];
    int pos = atomicAdd(&curs[(en >> 16) & 255], 1);
    img[pos] = (unsigned short)(en & 0xffffu);
  }
  __syncthreads();
  for (int i = t; i < n; i += 256)
    csr[base + i] = (int)img[i];
}

// ---------- FUSED gather-mean aggregation + MFMA GEMM, 16-row tiles ----------
// 6250 blocks x 4 waves. Per A-source: each wave aggregates 4 rows with the
// proven R4 intra-row pattern (64 lanes/row: 16 sub x 4 slots, 4-deep
// predicated unroll), stages bf16 means into a PADDED ROW-MAJOR LDS tile
// [16][136] (write: 64 contiguous words/row = 2-way, free; fragment read:
// ds_read_b128 <=8-way on only 4 reads/source). Then 8 MFMAs/wave/source on
// otherwise-idle matrix pipes. Eliminates the 75 MB agg round-trip and the
// separate gemm dispatch.
__global__ __launch_bounds__(256) void agg_gemm16(
    const unsigned short* __restrict__ xu_b, const unsigned short* __restrict__ xi_b,
    const int* __restrict__ rp0, const int* __restrict__ rp1, const int* __restrict__ rp2,
    const int* __restrict__ csr0, const int* __restrict__ csr1, const int* __restrict__ csr2,
    const unsigned short* __restrict__ wfrag,
    const float* __restrict__ b_lu, const float* __restrict__ b_li,
    float* __restrict__ out) {
  __shared__ unsigned short Asp[16 * LDA];   // 4352 B
  const int b = blockIdx.x;
  const int t = threadIdx.x;
  const int half = (b >= TBLK) ? 1 : 0;
  const int g0 = (half ? b - TBLK : b) * 16;
  const int lane = t & 63;
  const int w = t >> 6;
  const int sub = lane & 15, slot = lane >> 4;
  const int nsrc = half ? 2 : 3;
  const int widx0 = half ? 3 : 0;

  f32x4 acc[2] = {};

  for (int s = 0; s < nsrc; ++s) {
    if (s == nsrc - 1) {
      // self-loop source: direct vectorized stage (4 rows/wave, 16B/lane)
      const unsigned short* xs = half ? xi_b : xu_b;
      int r = w * 4 + slot;
      uint4 v = *reinterpret_cast<const uint4*>(xs + (size_t)(g0 + r) * FEAT + sub * 8);
      *reinterpret_cast<uint4*>(&Asp[r * LDA + sub * 8]) = v;
    } else {
      const int* rp; const int* csr; const unsigned short* xs;
      if (!half) {
        if (s == 0) { rp = rp0; csr = csr0; xs = xu_b; }
        else        { rp = rp1; csr = csr1; xs = xi_b; }
      } else        { rp = rp2; csr = csr2; xs = xu_b; }
      const uint4* __restrict__ xv = (const uint4*)xs;
      for (int ri = 0; ri < 4; ++ri) {
        int r = w * 4 + ri;
        int row = g0 + r;
        int beg = rp[row], end = rp[row + 1];
        float a0 = 0, a1 = 0, a2 = 0, a3 = 0, a4 = 0, a5 = 0, a6 = 0, a7 = 0;
#define ACC8(v) { \
    a0 += bflo(v.x); a1 += bfhi(v.x); \
    a2 += bflo(v.y); a3 += bfhi(v.y); \
    a4 += bflo(v.z); a5 += bfhi(v.z); \
    a6 += bflo(v.w); a7 += bfhi(v.w); }
        for (int e = beg + slot; e < end; e += 16) {
          int i0 = csr[e];
          uint4 v0 = xv[(size_t)i0 * 16 + sub];
          if (e + 4 < end) {
            int i1 = csr[e + 4];
            uint4 v1 = xv[(size_t)i1 * 16 + sub];
            if (e + 8 < end) {
              int i2 = csr[e + 8];
              uint4 v2 = xv[(size_t)i2 * 16 + sub];
              if (e + 12 < end) {
                int i3 = csr[e + 12];
                uint4 v3 = xv[(size_t)i3 * 16 + sub];
                ACC8(v3);
              }
              ACC8(v2);
            }
            ACC8(v1);
          }
          ACC8(v0);
        }
#undef ACC8
#define RED16_32(a) { a += __shfl_xor(a, 16, 64); a += __shfl_xor(a, 32, 64); }
        RED16_32(a0) RED16_32(a1) RED16_32(a2) RED16_32(a3)
        RED16_32(a4) RED16_32(a5) RED16_32(a6) RED16_32(a7)
#undef RED16_32
        if (slot == 0) {
          float rd = 1.0f / fmaxf((float)(end - beg), 1.0f);
          uint4 o;
          o.x = (unsigned)f2bf(a0 * rd) | ((unsigned)f2bf(a1 * rd) << 16);
          o.y = (unsigned)f2bf(a2 * rd) | ((unsigned)f2bf(a3 * rd) << 16);
          o.z = (unsigned)f2bf(a4 * rd) | ((unsigned)f2bf(a5 * rd) << 16);
          o.w = (unsigned)f2bf(a6 * rd) | ((unsigned)f2bf(a7 * rd) << 16);
          *reinterpret_cast<uint4*>(&Asp[r * LDA + sub * 8]) = o;
        }
      }
    }
    __syncthreads();
    // GEMM accumulate: A-frag from padded row-major LDS, B-frag from wfrag
    const unsigned short* wf = wfrag + (size_t)(widx0 + s) * (4 * 8 * 64 * 8);
#pragma unroll
    for (int kc = 0; kc < 4; ++kc) {
      short8 afr = *reinterpret_cast<const short8*>(
          &Asp[(lane & 15) * LDA + kc * 32 + (lane >> 4) * 8]);
#pragma unroll
      for (int ct = 0; ct < 2; ++ct) {
        int nt = 2 * w + ct;
        short8 bfr = *reinterpret_cast<const short8*>(wf + ((kc * 8 + nt) * 64 + lane) * 8);
        acc[ct] = __builtin_amdgcn_mfma_f32_16x16x32_bf16(afr, bfr, acc[ct], 0, 0, 0);
      }
    }
    __syncthreads();
  }

  // epilogue: bias + relu + store (C/D: col=lane&15, row=(lane>>4)*4+reg)
  const float* bias = half ? b_li : b_lu;
  int q = lane >> 4, nl = lane & 15;
  float bv[2] = { bias[w * 32 + nl], bias[w * 32 + 16 + nl] };
#pragma unroll
  for (int r = 0; r < 4; ++r) {
    size_t orow = (size_t)(half ? N_NODES : 0) + g0 + q * 4 + r;
#pragma unroll
    for (int ct = 0; ct < 2; ++ct) {
      float v = acc[ct][r] + bv[ct];
      out[orow * FEAT + w * 32 + ct * 16 + nl] = fmaxf(v, 0.f);
    }
  }
}

extern "C" void kernel_launch(void* const* d_in, const int* in_sizes, int n_in,
                              void* d_out, int out_size, void* d_ws, size_t ws_size,
                              hipStream_t stream) {
  const float* x_user = (const float*)d_in[0];
  const float* x_item = (const float*)d_in[1];
  const void* e_fol = d_in[2];
  const void* e_buy = d_in[3];
  const void* e_bb  = d_in[4];
  const float* W_fol = (const float*)d_in[5];
  const float* W_buy = (const float*)d_in[6];
  const float* W_bb  = (const float*)d_in[7];
  const float* W_lu  = (const float*)d_in[8];
  const float* b_lu  = (const float*)d_in[9];
  const float* W_li  = (const float*)d_in[10];
  const float* b_li  = (const float*)d_in[11];
  float* out = (float*)d_out;

  // ws: part (29.5 MB) at base; bf16 x / wfrag above; ints at +64 MB.
  unsigned short* wsu = (unsigned short*)d_ws;
  unsigned short* xu_b  = wsu + 19200000;
  unsigned short* xi_b  = wsu + 25600000;
  unsigned short* wfrag = wsu + 32000000;      // 81920 ushorts
  unsigned* part = (unsigned*)d_ws;            // NBUKT*KPART*SEGCAP = 7,375,368 uints
  int* ip = (int*)d_ws + 16040960;
  int* csr0 = ip;
  int* csr1 = ip + 600000;
  int* csr2 = ip + 1200000;
  int* rp0  = ip + 1800000;     // 50016 each
  int* rp1  = rp0 + 50016;
  int* rp2  = rp1 + 50016;
  int* countsT = ip + 1950048;  // NBUKT*KPART = 131712
  int* btot    = ip + 2081760;  // 588

  hipMemsetAsync(btot, 0, NBUKT * sizeof(int), stream);

  part_cvt<<<KPART + NB_CVT + NB_W, 256, 0, stream>>>(
      e_fol, e_bb, e_buy, part, countsT, btot, x_user, x_item,
      W_fol, W_bb, W_lu, W_buy, W_li, xu_b, xi_b, wfrag);

  csr_build<<<3 * NBUK, 256, 0, stream>>>(part, countsT, btot,
                                          csr0, csr1, csr2, rp0, rp1, rp2);

  agg_gemm16<<<2 * TBLK, 256, 0, stream>>>(
      xu_b, xi_b, rp0, rp1, rp2, csr0, csr1, csr2,
      wfrag, b_lu, b_li, out);
}

// Round 8
// 253.040 us; speedup vs baseline: 1.1788x; 1.0181x over previous
//
#include <hip/hip_runtime.h>

#define N_NODES 50000
#define FEAT    128
#define NEDGE   600000

#define NBUK    196        // buckets per rel (256 dsts each); 588 total
#define NBUKT   588
#define BUKCAP  4096       // bucket total: mean 3061, sigma 55 -> 19 sigma
#define KPART   224        // partition slices per rel
#define NB_PART 672        // 3 rels x KPART, one rel per block
#define SEGCAP  44         // mean 13.7; Poisson tail @44 ~ 4e-11/seg, 5e-6 overall
#define SEGQ    11         // SEGCAP/4 uint4s
#define EPB     2679       // ceil(600000/224)
#define NB_CVT  6250       // 2 x 3125
#define NB_W    5

#define TBLK    3125       // 16-row tiles per half (50000/16 exact)
#define LDA     136        // padded LDS row stride (ushorts); 272 B, 16B-aligned

typedef __attribute__((ext_vector_type(8))) short short8;
typedef __attribute__((ext_vector_type(4))) float f32x4;

// ---------- bf16 helpers ----------
__device__ __forceinline__ unsigned short f2bf(float f) {
  unsigned u = __float_as_uint(f);
  return (unsigned short)((u + 0x7fffu + ((u >> 16) & 1u)) >> 16);
}
__device__ __forceinline__ float bflo(unsigned u) { return __uint_as_float(u << 16); }
__device__ __forceinline__ float bfhi(unsigned u) { return __uint_as_float(u & 0xffff0000u); }

__device__ __forceinline__ int edge_at(const void* __restrict__ edges, long i, int is64) {
  return is64 ? (int)((const long long*)edges)[i] : ((const int*)edges)[i];
}

// ---------- fused: rel-split LDS-staged partition + x->bf16 cvt + W pack ----------
// Partition: ONE rel per block (672 blocks) -> 3x critical-path parallelism
// vs the old 224-blocks x 3-serial-passes form. Segments staged in LDS,
// flushed as contiguous uint4 runs.
// part layout TRANSPOSED: part[((rel*NBUK+bucket)*KPART + kb)*SEGCAP + pos]
// -> a bucket's 224 segments are one contiguous ~39 KB region for csr_build.
__global__ __launch_bounds__(256) void part_cvt(
    const void* __restrict__ e0, const void* __restrict__ e1, const void* __restrict__ e2,
    unsigned* __restrict__ part, int* __restrict__ countsT, int* __restrict__ btot,
    const float* __restrict__ xu, const float* __restrict__ xi,
    const float* __restrict__ W_fol, const float* __restrict__ W_bb,
    const float* __restrict__ W_lu, const float* __restrict__ W_buy,
    const float* __restrict__ W_li,
    unsigned short* __restrict__ xu_b, unsigned short* __restrict__ xi_b,
    unsigned short* __restrict__ wfrag) {
  __shared__ unsigned stg[NBUK * SEGCAP];   // 34496 B staging
  __shared__ int scnt[NBUK];
  __shared__ int s_is64;
  int b = blockIdx.x;
  int t = threadIdx.x;
  if (b < NB_PART) {
    int rel = b / KPART;
    int kb = b - rel * KPART;
    // inline dtype detect: wave 0 samples the first 64 u32-pair hi words
    if (t < 64) {
      unsigned hi = ((const unsigned*)e0)[2 * t + 1];
      unsigned long long any = __ballot(hi != 0u);
      if (t == 0) s_is64 = (any == 0ull) ? 1 : 0;
    }
    for (int i = t; i < NBUK; i += 256) scnt[i] = 0;
    __syncthreads();
    int is64 = s_is64;
    const void* ep = (rel == 0) ? e0 : (rel == 1) ? e1 : e2;
    int ebase = kb * EPB;
    int eend = min(ebase + EPB, NEDGE);
    for (int ei = ebase + t; ei < eend; ei += 256) {
      int src = edge_at(ep, ei, is64);
      int dst = edge_at(ep, (long)NEDGE + ei, is64);
      int bk = dst >> 8;
      int pos = atomicAdd(&scnt[bk], 1);
      if (pos < SEGCAP)
        stg[bk * SEGCAP + pos] = (unsigned)src | ((unsigned)(dst & 255) << 16);
    }
    __syncthreads();
    // coalesced flush: full segments (stale tail entries bounded by countsT)
    const uint4* s4 = (const uint4*)stg;
    uint4* p4 = (uint4*)part;
    for (int i = t; i < NBUK * SEGQ; i += 256) {
      int bk = i / SEGQ, j = i - bk * SEGQ;
      p4[((size_t)((rel * NBUK + bk) * KPART + kb)) * SEGQ + j] = s4[i];
    }
    for (int i = t; i < NBUK; i += 256) {
      int c = min(scnt[i], SEGCAP);
      countsT[(rel * NBUK + i) * KPART + kb] = c;
      atomicAdd(&btot[rel * NBUK + i], c);   // cross-block totals (pre-zeroed)
    }
  } else if (b < NB_PART + NB_CVT) {
    int cb = b - NB_PART;
    const float* src = (cb < 3125) ? xu : xi;
    unsigned short* dst = (cb < 3125) ? xu_b : xi_b;
    int lb = (cb < 3125) ? cb : cb - 3125;
    size_t base = ((size_t)lb * 256 + t) * 8;
    float4 v0 = *reinterpret_cast<const float4*>(src + base);
    float4 v1 = *reinterpret_cast<const float4*>(src + base + 4);
    uint4 o;
    o.x = f2bf(v0.x) | ((unsigned)f2bf(v0.y) << 16);
    o.y = f2bf(v0.z) | ((unsigned)f2bf(v0.w) << 16);
    o.z = f2bf(v1.x) | ((unsigned)f2bf(v1.y) << 16);
    o.w = f2bf(v1.z) | ((unsigned)f2bf(v1.w) << 16);
    *reinterpret_cast<uint4*>(dst + base) = o;
  } else {
    int s = b - (NB_PART + NB_CVT);
    const float* W = (s == 0) ? W_fol : (s == 1) ? W_bb : (s == 2) ? W_lu
                    : (s == 3) ? W_buy : W_li;
    for (int idx = t; idx < 16384; idx += 256) {
      int k = idx >> 7, n = idx & 127;
      int kc = k >> 5, q = (k >> 3) & 3, j = k & 7;
      int nt = n >> 4, nl = n & 15;
      wfrag[((((size_t)s * 4 + kc) * 8 + nt) * 64 + (q * 16 + nl)) * 8 + j] = f2bf(W[idx]);
    }
  }
}

// ---------- block scan helper ----------
__device__ __forceinline__ int block_scan_incl(int v, int* wsum) {
  int lane = threadIdx.x & 63, wid = threadIdx.x >> 6;
#pragma unroll
  for (int d = 1; d < 64; d <<= 1) {
    int n = __shfl_up(v, d, 64);
    if (lane >= d) v += n;
  }
  if (lane == 63) wsum[wid] = v;
  __syncthreads();
  if (threadIdx.x < 4) {
    int s = wsum[threadIdx.x];
#pragma unroll
    for (int d = 1; d < 4; d <<= 1) {
      int n = __shfl_up(s, d, 64);
      if ((int)threadIdx.x >= d) s += n;
    }
    wsum[threadIdx.x] = s;
  }
  __syncthreads();
  return v + (wid ? wsum[wid - 1] : 0);
}

// ---------- per-bucket CSR build ----------
__global__ __launch_bounds__(256) void csr_build(
    const unsigned* __restrict__ part, const int* __restrict__ countsT,
    const int* __restrict__ btot,
    int* __restrict__ csr0, int* __restrict__ csr1, int* __restrict__ csr2,
    int* __restrict__ rp0, int* __restrict__ rp1, int* __restrict__ rp2) {
  __shared__ int segcnt[256];
  __shared__ int segoff[256];
  __shared__ int wsum[4];
  __shared__ int nTot;
  __shared__ int sBase;
  __shared__ unsigned stage[BUKCAP];     // 16 KB
  __shared__ int cnt[256];
  __shared__ int curs[256];
  __shared__ unsigned short img[BUKCAP]; // 8 KB
  int blk = blockIdx.x;
  int rel = blk / NBUK, lb = blk - rel * NBUK;
  int* __restrict__ csr = (rel == 0) ? csr0 : (rel == 1) ? csr1 : csr2;
  int* __restrict__ rp  = (rel == 0) ? rp0  : (rel == 1) ? rp1  : rp2;
  int t = threadIdx.x;

  int c = (t < KPART) ? countsT[(size_t)blk * KPART + t] : 0;  // issue early
  int bt = (t < NBUK) ? btot[rel * NBUK + t] : 0;
  int cB = min(bt, BUKCAP);
  int inclB = block_scan_incl(cB, wsum);
  if (t == lb) sBase = inclB - cB;
  if (lb == 0 && t == 0) rp[N_NODES] = NEDGE;
  __syncthreads();
  int base = sBase;

  int incl = block_scan_incl(c, wsum);
  segcnt[t] = c;
  segoff[t] = incl - c;
  if (t == 255) nTot = incl;
  __syncthreads();
  int n = min(nTot, BUKCAP);

  const unsigned* __restrict__ reg = part + (size_t)blk * KPART * SEGCAP;
  for (int i = t; i < KPART * SEGCAP; i += 256) {
    int k = i / SEGCAP, j = i - k * SEGCAP;
    if (j < segcnt[k]) stage[segoff[k] + j] = reg[i];
  }
  cnt[t] = 0;
  __syncthreads();

  for (int i = t; i < n; i += 256)
    atomicAdd(&cnt[(stage[i] >> 16) & 255], 1);
  __syncthreads();
  int c2 = cnt[t];
  int incl2 = block_scan_incl(c2, wsum);
  int excl2 = incl2 - c2;
  curs[t] = excl2;
  int d = lb * 256 + t;
  if (d < N_NODES) rp[d] = base + excl2;
  __syncthreads();

  for (int i = t; i < n; i += 256) {
    unsigned en = stage[i];
    int pos = atomicAdd(&curs[(en >> 16) & 255], 1);
    img[pos] = (unsigned short)(en & 0xffffu);
  }
  __syncthreads();
  for (int i = t; i < n; i += 256)
    csr[base + i] = (int)img[i];
}

// ---------- FUSED gather-mean aggregation + MFMA GEMM, 16-row tiles ----------
// (unchanged from R7: 6250 blocks x 4 waves; R4 intra-row gather pattern;
// padded row-major LDS stage; 8 MFMAs/wave/source on idle matrix pipes.)
__global__ __launch_bounds__(256) void agg_gemm16(
    const unsigned short* __restrict__ xu_b, const unsigned short* __restrict__ xi_b,
    const int* __restrict__ rp0, const int* __restrict__ rp1, const int* __restrict__ rp2,
    const int* __restrict__ csr0, const int* __restrict__ csr1, const int* __restrict__ csr2,
    const unsigned short* __restrict__ wfrag,
    const float* __restrict__ b_lu, const float* __restrict__ b_li,
    float* __restrict__ out) {
  __shared__ unsigned short Asp[16 * LDA];   // 4352 B
  const int b = blockIdx.x;
  const int t = threadIdx.x;
  const int half = (b >= TBLK) ? 1 : 0;
  const int g0 = (half ? b - TBLK : b) * 16;
  const int lane = t & 63;
  const int w = t >> 6;
  const int sub = lane & 15, slot = lane >> 4;
  const int nsrc = half ? 2 : 3;
  const int widx0 = half ? 3 : 0;

  f32x4 acc[2] = {};

  for (int s = 0; s < nsrc; ++s) {
    if (s == nsrc - 1) {
      // self-loop source: direct vectorized stage (4 rows/wave, 16B/lane)
      const unsigned short* xs = half ? xi_b : xu_b;
      int r = w * 4 + slot;
      uint4 v = *reinterpret_cast<const uint4*>(xs + (size_t)(g0 + r) * FEAT + sub * 8);
      *reinterpret_cast<uint4*>(&Asp[r * LDA + sub * 8]) = v;
    } else {
      const int* rp; const int* csr; const unsigned short* xs;
      if (!half) {
        if (s == 0) { rp = rp0; csr = csr0; xs = xu_b; }
        else        { rp = rp1; csr = csr1; xs = xi_b; }
      } else        { rp = rp2; csr = csr2; xs = xu_b; }
      const uint4* __restrict__ xv = (const uint4*)xs;
      for (int ri = 0; ri < 4; ++ri) {
        int r = w * 4 + ri;
        int row = g0 + r;
        int beg = rp[row], end = rp[row + 1];
        float a0 = 0, a1 = 0, a2 = 0, a3 = 0, a4 = 0, a5 = 0, a6 = 0, a7 = 0;
#define ACC8(v) { \
    a0 += bflo(v.x); a1 += bfhi(v.x); \
    a2 += bflo(v.y); a3 += bfhi(v.y); \
    a4 += bflo(v.z); a5 += bfhi(v.z); \
    a6 += bflo(v.w); a7 += bfhi(v.w); }
        for (int e = beg + slot; e < end; e += 16) {
          int i0 = csr[e];
          uint4 v0 = xv[(size_t)i0 * 16 + sub];
          if (e + 4 < end) {
            int i1 = csr[e + 4];
            uint4 v1 = xv[(size_t)i1 * 16 + sub];
            if (e + 8 < end) {
              int i2 = csr[e + 8];
              uint4 v2 = xv[(size_t)i2 * 16 + sub];
              if (e + 12 < end) {
                int i3 = csr[e + 12];
                uint4 v3 = xv[(size_t)i3 * 16 + sub];
                ACC8(v3);
              }
              ACC8(v2);
            }
            ACC8(v1);
          }
          ACC8(v0);
        }
#undef ACC8
#define RED16_32(a) { a += __shfl_xor(a, 16, 64); a += __shfl_xor(a, 32, 64); }
        RED16_32(a0) RED16_32(a1) RED16_32(a2) RED16_32(a3)
        RED16_32(a4) RED16_32(a5) RED16_32(a6) RED16_32(a7)
#undef RED16_32
        if (slot == 0) {
          float rd = 1.0f / fmaxf((float)(end - beg), 1.0f);
          uint4 o;
          o.x = (unsigned)f2bf(a0 * rd) | ((unsigned)f2bf(a1 * rd) << 16);
          o.y = (unsigned)f2bf(a2 * rd) | ((unsigned)f2bf(a3 * rd) << 16);
          o.z = (unsigned)f2bf(a4 * rd) | ((unsigned)f2bf(a5 * rd) << 16);
          o.w = (unsigned)f2bf(a6 * rd) | ((unsigned)f2bf(a7 * rd) << 16);
          *reinterpret_cast<uint4*>(&Asp[r * LDA + sub * 8]) = o;
        }
      }
    }
    __syncthreads();
    // GEMM accumulate: A-frag from padded row-major LDS, B-frag from wfrag
    const unsigned short* wf = wfrag + (size_t)(widx0 + s) * (4 * 8 * 64 * 8);
#pragma unroll
    for (int kc = 0; kc < 4; ++kc) {
      short8 afr = *reinterpret_cast<const short8*>(
          &Asp[(lane & 15) * LDA + kc * 32 + (lane >> 4) * 8]);
#pragma unroll
      for (int ct = 0; ct < 2; ++ct) {
        int nt = 2 * w + ct;
        short8 bfr = *reinterpret_cast<const short8*>(wf + ((kc * 8 + nt) * 64 + lane) * 8);
        acc[ct] = __builtin_amdgcn_mfma_f32_16x16x32_bf16(afr, bfr, acc[ct], 0, 0, 0);
      }
    }
    __syncthreads();
  }

  // epilogue: bias + relu + store (C/D: col=lane&15, row=(lane>>4)*4+reg)
  const float* bias = half ? b_li : b_lu;
  int q = lane >> 4, nl = lane & 15;
  float bv[2] = { bias[w * 32 + nl], bias[w * 32 + 16 + nl] };
#pragma unroll
  for (int r = 0; r < 4; ++r) {
    size_t orow = (size_t)(half ? N_NODES : 0) + g0 + q * 4 + r;
#pragma unroll
    for (int ct = 0; ct < 2; ++ct) {
      float v = acc[ct][r] + bv[ct];
      out[orow * FEAT + w * 32 + ct * 16 + nl] = fmaxf(v, 0.f);
    }
  }
}

extern "C" void kernel_launch(void* const* d_in, const int* in_sizes, int n_in,
                              void* d_out, int out_size, void* d_ws, size_t ws_size,
                              hipStream_t stream) {
  const float* x_user = (const float*)d_in[0];
  const float* x_item = (const float*)d_in[1];
  const void* e_fol = d_in[2];
  const void* e_buy = d_in[3];
  const void* e_bb  = d_in[4];
  const float* W_fol = (const float*)d_in[5];
  const float* W_buy = (const float*)d_in[6];
  const float* W_bb  = (const float*)d_in[7];
  const float* W_lu  = (const float*)d_in[8];
  const float* b_lu  = (const float*)d_in[9];
  const float* W_li  = (const float*)d_in[10];
  const float* b_li  = (const float*)d_in[11];
  float* out = (float*)d_out;

  // ws: part (23.2 MB) at base; bf16 x / wfrag above; ints at +64 MB.
  unsigned short* wsu = (unsigned short*)d_ws;
  unsigned short* xu_b  = wsu + 19200000;
  unsigned short* xi_b  = wsu + 25600000;
  unsigned short* wfrag = wsu + 32000000;      // 81920 ushorts
  unsigned* part = (unsigned*)d_ws;            // NBUKT*KPART*SEGCAP = 5,795,328 uints
  int* ip = (int*)d_ws + 16040960;
  int* csr0 = ip;
  int* csr1 = ip + 600000;
  int* csr2 = ip + 1200000;
  int* rp0  = ip + 1800000;     // 50016 each
  int* rp1  = rp0 + 50016;
  int* rp2  = rp1 + 50016;
  int* countsT = ip + 1950048;  // NBUKT*KPART = 131712
  int* btot    = ip + 2081760;  // 588

  hipMemsetAsync(btot, 0, NBUKT * sizeof(int), stream);

  // rel order preserved from prior rounds: rel0=follows, rel1=bought_by, rel2=buys
  part_cvt<<<NB_PART + NB_CVT + NB_W, 256, 0, stream>>>(
      e_fol, e_bb, e_buy, part, countsT, btot, x_user, x_item,
      W_fol, W_bb, W_lu, W_buy, W_li, xu_b, xi_b, wfrag);

  csr_build<<<3 * NBUK, 256, 0, stream>>>(part, countsT, btot,
                                          csr0, csr1, csr2, rp0, rp1, rp2);

  agg_gemm16<<<2 * TBLK, 256, 0, stream>>>(
      xu_b, xi_b, rp0, rp1, rp2, csr0, csr1, csr2,
      wfrag, b_lu, b_li, out);
}